// Round 11
// baseline (184.076 us; speedup 1.0000x reference)
//
#include <hip/hip_runtime.h>
#include <hip/hip_cooperative_groups.h>
#include <math.h>

namespace cg = cooperative_groups;

// Problem constants (from reference setup_inputs)
constexpr int B  = 8;
constexpr int C  = 256;
constexpr int Q  = 85;              // C/D; channel->dim: d = min(c/Q, 2)
constexpr int NS0 = 16384, NS1 = 4096, NS2 = 1024, NS3 = 256;
constexpr int PAR = NS1 + NS2 + NS3;        // parents, levels 0-2
constexpr int SLT = NS0 + NS1 + NS2;        // slots (= children), levels 0-2
constexpr int GRID_W = 512;                 // coop grid: 2 blocks/CU, co-resident

__device__ __forceinline__ int cdim(int c) {
    int d = c / Q;
    return d > 2 ? 2 : d;
}

struct CP {
    const int   *idx0, *idx1, *idx2;
    const float *c0, *c1, *c2, *c3, *c4;
    unsigned    *cnt;     // (B,PAR) never initialized (mod-4 trick)
    float4      *dslot;   // (B,SLT)
    float       *w3;      // (B,256,3)
    float       *z4;      // (B,3)
    float       *Wn;      // (B,3,NS0)
};

// Sibling-group weight: given the 4 children of one parent (from dslot) and a
// target child node id, compute the target's per-dim weight and the per-dim
// sum over all 4 children. Identical arithmetic to the previous kernels.
__device__ __forceinline__ void sib_w(float4 c0, float4 c1, float4 c2, float4 c3,
                                      int target,
                                      float& wt0, float& wt1, float& wt2,
                                      float& zs0, float& zs1, float& zs2) {
    float mx0 = fmaxf(fmaxf(c0.x, c1.x), fmaxf(c2.x, c3.x));
    float mn0 = fminf(fminf(c0.x, c1.x), fminf(c2.x, c3.x));
    float mx1 = fmaxf(fmaxf(c0.y, c1.y), fmaxf(c2.y, c3.y));
    float mn1 = fminf(fminf(c0.y, c1.y), fminf(c2.y, c3.y));
    float mx2 = fmaxf(fmaxf(c0.z, c1.z), fmaxf(c2.z, c3.z));
    float mn2 = fminf(fminf(c0.z, c1.z), fminf(c2.z, c3.z));
    float pos0 = fmaxf(mx0, 0.f), neg0 = fminf(mn0, 0.f);
    float pos1 = fmaxf(mx1, 0.f), neg1 = fminf(mn1, 0.f);
    float pos2 = fmaxf(mx2, 0.f), neg2 = fminf(mn2, 0.f);

    zs0 = zs1 = zs2 = 0.f;
    wt0 = wt1 = wt2 = 0.f;
    float4 chs[4] = {c0, c1, c2, c3};
#pragma unroll
    for (int k = 0; k < 4; ++k) {
        float d0 = chs[k].x, d1 = chs[k].y, d2 = chs[k].z;
        int   n  = __float_as_int(chs[k].w);
        float wv0 = 1.f - fabsf(d0) / (fabsf(d0 >= 0.f ? pos0 : neg0) + 1e-6f);
        float wv1 = 1.f - fabsf(d1) / (fabsf(d1 >= 0.f ? pos1 : neg1) + 1e-6f);
        float wv2 = 1.f - fabsf(d2) / (fabsf(d2 >= 0.f ? pos2 : neg2) + 1e-6f);
        zs0 += wv0; zs1 += wv1; zs2 += wv2;
        if (n == target) { wt0 = wv0; wt1 = wv1; wt2 = wv2; }
    }
}

// ---------------------------------------------------------------------------
// Cooperative kernel: whole weights path in ONE dispatch.
// Phase A: blocks 0-7 compute level-3 (root) weights via LDS tree reduction;
//          all blocks grid-stride over the 172K invert items (levels 0-2):
//          slot = atomicAdd(cnt)&3 (correct from ANY start value -> no init).
// grid.sync()
// Phase B: one item per level-1 node (32K): reads its 4 leaves + its parent's
//          sibling group + grandparent's sibling group from dslot, computes
//          w1/z2, w2/z3 locally (redundant x4/x16, L2-absorbed), chains with
//          w3/z4, writes the 4 leaves' effective weights Wn.
// NO early returns anywhere (all threads must reach grid.sync()).
// ---------------------------------------------------------------------------
__global__ __launch_bounds__(256)
void weights_coop_kernel(CP P) {
    __shared__ float sm[3][256];
    __shared__ float sn[3][256];
    cg::grid_group grid = cg::this_grid();

    // ---- Phase A1: level-3 weights (blocks 0..7, one per batch) ----
    if (blockIdx.x < 8) {
        int b = blockIdx.x;
        int n = threadIdx.x;
        float pc0 = P.c4[b * 3 + 0], pc1 = P.c4[b * 3 + 1], pc2 = P.c4[b * 3 + 2];
        const float* cp = &P.c3[((size_t)(b * 256 + n)) * 3];
        float d0 = cp[0] - pc0, d1 = cp[1] - pc1, d2 = cp[2] - pc2;
        sm[0][n] = d0; sm[1][n] = d1; sm[2][n] = d2;
        sn[0][n] = d0; sn[1][n] = d1; sn[2][n] = d2;
        __syncthreads();
        for (int s = 128; s > 0; s >>= 1) {
            if (n < s) {
#pragma unroll
                for (int d = 0; d < 3; ++d) {
                    sm[d][n] = fmaxf(sm[d][n], sm[d][n + s]);
                    sn[d][n] = fminf(sn[d][n], sn[d][n + s]);
                }
            }
            __syncthreads();
        }
        float pos0 = fmaxf(sm[0][0], 0.f), pos1 = fmaxf(sm[1][0], 0.f), pos2 = fmaxf(sm[2][0], 0.f);
        float neg0 = fminf(sn[0][0], 0.f), neg1 = fminf(sn[1][0], 0.f), neg2 = fminf(sn[2][0], 0.f);
        __syncthreads();

        float w0 = 1.f - fabsf(d0) / (fabsf(d0 >= 0.f ? pos0 : neg0) + 1e-6f);
        float w1 = 1.f - fabsf(d1) / (fabsf(d1 >= 0.f ? pos1 : neg1) + 1e-6f);
        float w2 = 1.f - fabsf(d2) / (fabsf(d2 >= 0.f ? pos2 : neg2) + 1e-6f);
        float* wp = &P.w3[((size_t)(b * 256 + n)) * 3];
        wp[0] = w0; wp[1] = w1; wp[2] = w2;

        sm[0][n] = w0; sm[1][n] = w1; sm[2][n] = w2;
        __syncthreads();
        for (int s = 128; s > 0; s >>= 1) {
            if (n < s) {
#pragma unroll
                for (int d = 0; d < 3; ++d) sm[d][n] += sm[d][n + s];
            }
            __syncthreads();
        }
        if (n == 0) {
            P.z4[b * 3 + 0] = sm[0][0];
            P.z4[b * 3 + 1] = sm[1][0];
            P.z4[b * 3 + 2] = sm[2][0];
        }
    }

    // ---- Phase A2: invert levels 0-2, grid-stride ----
    {
        const int u0 = B * NS0;            // end of level-0 items
        const int u1 = u0 + B * NS1;       // end of level-1 items
        const int utot = u1 + B * NS2;
        for (int u = blockIdx.x * 256 + threadIdx.x; u < utot; u += GRID_W * 256) {
            const int* idx; const float *cc, *cn;
            int N, Nn, cbase, sbase, v;
            if (u < u0)      { v = u;      idx = P.idx0; cc = P.c0; cn = P.c1; N = NS0; Nn = NS1; cbase = 0;         sbase = 0; }
            else if (u < u1) { v = u - u0; idx = P.idx1; cc = P.c1; cn = P.c2; N = NS1; Nn = NS2; cbase = NS1;       sbase = NS0; }
            else             { v = u - u1; idx = P.idx2; cc = P.c2; cn = P.c3; N = NS2; Nn = NS3; cbase = NS1 + NS2; sbase = NS0 + NS1; }
            int b = v / N;
            int n = v - b * N;
            int j = idx[(size_t)b * N + n];
            int pj = b * Nn + j;

            unsigned o = atomicAdd(&P.cnt[(size_t)b * PAR + cbase + j], 1u);
            int slot = (int)(o & 3u);

            float4 dv;
            dv.x = cc[((size_t)b * N + n) * 3 + 0] - cn[(size_t)pj * 3 + 0];
            dv.y = cc[((size_t)b * N + n) * 3 + 1] - cn[(size_t)pj * 3 + 1];
            dv.z = cc[((size_t)b * N + n) * 3 + 2] - cn[(size_t)pj * 3 + 2];
            dv.w = __int_as_float(n);
            P.dslot[((size_t)b * SLT + sbase + (size_t)j * 4) + slot] = dv;
        }
    }

    __threadfence();
    grid.sync();

    // ---- Phase B: per level-1 node, compute full chain and write Wn ----
    for (int t = blockIdx.x * 256 + threadIdx.x; t < B * NS1; t += GRID_W * 256) {
        int b = t / NS1;
        int j = t - b * NS1;

        // Own 4 leaves.
        const float4* dp0 = &P.dslot[(size_t)b * SLT + (size_t)j * 4];
        float4 l0 = dp0[0], l1 = dp0[1], l2 = dp0[2], l3 = dp0[3];

        float mx0 = fmaxf(fmaxf(l0.x, l1.x), fmaxf(l2.x, l3.x));
        float mn0 = fminf(fminf(l0.x, l1.x), fminf(l2.x, l3.x));
        float mx1 = fmaxf(fmaxf(l0.y, l1.y), fmaxf(l2.y, l3.y));
        float mn1 = fminf(fminf(l0.y, l1.y), fminf(l2.y, l3.y));
        float mx2 = fmaxf(fmaxf(l0.z, l1.z), fmaxf(l2.z, l3.z));
        float mn2 = fminf(fminf(l0.z, l1.z), fminf(l2.z, l3.z));
        float pos0 = fmaxf(mx0, 0.f), neg0 = fminf(mn0, 0.f);
        float pos1 = fmaxf(mx1, 0.f), neg1 = fminf(mn1, 0.f);
        float pos2 = fmaxf(mx2, 0.f), neg2 = fminf(mn2, 0.f);

        float wv0[4], wv1[4], wv2[4];
        int   nid[4];
        float zz0 = 0.f, zz1 = 0.f, zz2 = 0.f;
        float4 chs[4] = {l0, l1, l2, l3};
#pragma unroll
        for (int k = 0; k < 4; ++k) {
            float d0 = chs[k].x, d1 = chs[k].y, d2 = chs[k].z;
            nid[k] = __float_as_int(chs[k].w);
            wv0[k] = 1.f - fabsf(d0) / (fabsf(d0 >= 0.f ? pos0 : neg0) + 1e-6f);
            wv1[k] = 1.f - fabsf(d1) / (fabsf(d1 >= 0.f ? pos1 : neg1) + 1e-6f);
            wv2[k] = 1.f - fabsf(d2) / (fabsf(d2 >= 0.f ? pos2 : neg2) + 1e-6f);
            zz0 += wv0[k]; zz1 += wv1[k]; zz2 += wv2[k];
        }

        // Parent (level-1 sibling group under L2 node a2).
        int a2 = P.idx1[(size_t)b * NS1 + j];
        const float4* dp1 = &P.dslot[(size_t)b * SLT + NS0 + (size_t)a2 * 4];
        float w1t0, w1t1, w1t2, z20, z21, z22;
        sib_w(dp1[0], dp1[1], dp1[2], dp1[3], j, w1t0, w1t1, w1t2, z20, z21, z22);

        // Grandparent (level-2 sibling group under L3 node a3).
        int a3 = P.idx2[(size_t)b * NS2 + a2];
        const float4* dp2 = &P.dslot[(size_t)b * SLT + NS0 + NS1 + (size_t)a3 * 4];
        float w2t0, w2t1, w2t2, z30, z31, z32;
        sib_w(dp2[0], dp2[1], dp2[2], dp2[3], a2, w2t0, w2t1, w2t2, z30, z31, z32);

        const float* w3p = &P.w3[((size_t)b * 256 + a3) * 3];
        float U0 = w1t0 / (z20 + 1e-6f) * w2t0 / (z30 + 1e-6f) * w3p[0] / (P.z4[b * 3 + 0] + 1e-6f);
        float U1 = w1t1 / (z21 + 1e-6f) * w2t1 / (z31 + 1e-6f) * w3p[1] / (P.z4[b * 3 + 1] + 1e-6f);
        float U2 = w1t2 / (z22 + 1e-6f) * w2t2 / (z32 + 1e-6f) * w3p[2] / (P.z4[b * 3 + 2] + 1e-6f);

        float r0 = U0 / (zz0 + 1e-6f);
        float r1 = U1 / (zz1 + 1e-6f);
        float r2 = U2 / (zz2 + 1e-6f);

        float* Wb0 = P.Wn + ((size_t)(b * 3 + 0)) * NS0;
        float* Wb1 = P.Wn + ((size_t)(b * 3 + 1)) * NS0;
        float* Wb2 = P.Wn + ((size_t)(b * 3 + 2)) * NS0;
#pragma unroll
        for (int k = 0; k < 4; ++k) {
            int n = nid[k];
            Wb0[n] = wv0[k] * r0;
            Wb1[n] = wv1[k] * r1;
            Wb2[n] = wv2[k] * r2;
        }
    }
}

// ---------------------------------------------------------------------------
// Final: the whole hierarchy as one weighted reduction over leaves.
// out[b][c] = cbrt( sum_n max(x[b][c][n],eps)^3 * Wn[b][d(c)][n] )
// One block per (b,c); x read coalesced float4 exactly once.
// ---------------------------------------------------------------------------
__global__ void final_kernel(const float* __restrict__ x,   // (B,C,NS0)
                             const float* __restrict__ Wn,  // (B,3,NS0)
                             float* __restrict__ out,       // (B,C)
                             const float* __restrict__ p_arr) {
    __shared__ float sred[256];
    int bc = blockIdx.x;
    int b = bc / C;
    int c = bc - b * C;
    int d = cdim(c);
    float p = p_arr[0];
    bool p3 = (p == 3.0f);

    const float4* xr = (const float4*)(x + (size_t)bc * NS0);
    const float4* wr = (const float4*)(Wn + ((size_t)(b * 3 + d)) * NS0);

    float acc = 0.f;
#pragma unroll 8
    for (int i = threadIdx.x; i < NS0 / 4; i += 256) {
        float4 xv = xr[i];
        float4 wv = wr[i];
        float v0 = fmaxf(xv.x, 1e-6f);
        float v1 = fmaxf(xv.y, 1e-6f);
        float v2 = fmaxf(xv.z, 1e-6f);
        float v3 = fmaxf(xv.w, 1e-6f);
        float s0 = p3 ? v0 * v0 * v0 : powf(v0, p);
        float s1 = p3 ? v1 * v1 * v1 : powf(v1, p);
        float s2 = p3 ? v2 * v2 * v2 : powf(v2, p);
        float s3 = p3 ? v3 * v3 * v3 : powf(v3, p);
        acc = fmaf(s0, wv.x, acc);
        acc = fmaf(s1, wv.y, acc);
        acc = fmaf(s2, wv.z, acc);
        acc = fmaf(s3, wv.w, acc);
    }
    sred[threadIdx.x] = acc;
    __syncthreads();
    for (int s = 128; s > 0; s >>= 1) {
        if (threadIdx.x < s) sred[threadIdx.x] += sred[threadIdx.x + s];
        __syncthreads();
    }
    if (threadIdx.x == 0) {
        float t = sred[0];
        out[bc] = p3 ? cbrtf(t) : powf(t, 1.0f / p);
    }
}

// ---------------------------------------------------------------------------
extern "C" void kernel_launch(void* const* d_in, const int* in_sizes, int n_in,
                              void* d_out, int out_size, void* d_ws, size_t ws_size,
                              hipStream_t stream) {
    const float* x      = (const float*)d_in[0];
    const int*   idx0   = (const int*)d_in[1];
    const int*   idx1   = (const int*)d_in[2];
    const int*   idx2   = (const int*)d_in[3];
    // d_in[4] (idx3) unused: level-3 parent is the single root node.
    const float* coords0 = (const float*)d_in[5];
    const float* coords1 = (const float*)d_in[6];
    const float* coords2 = (const float*)d_in[7];
    const float* coords3 = (const float*)d_in[8];
    const float* coords4 = (const float*)d_in[9];
    const float* p = (const float*)d_in[10];

    // Workspace carve-up (256B aligned)
    char* ws = (char*)d_ws;
    size_t off = 0;
    auto alloc = [&](size_t bytes) -> void* {
        off = (off + 255) & ~(size_t)255;
        void* r = ws + off;
        off += bytes;
        return r;
    };

    unsigned* cnt  = (unsigned*)alloc((size_t)B * PAR * sizeof(unsigned)); // never initialized (mod-4 trick)
    float4*  dslot = (float4*)alloc((size_t)B * SLT * sizeof(float4));
    float* w3 = (float*)alloc((size_t)B * NS3 * 3 * sizeof(float));
    float* z4 = (float*)alloc((size_t)B * 1   * 3 * sizeof(float));
    float* Wn = (float*)alloc((size_t)B * 3 * NS0 * sizeof(float));

    CP P;
    P.idx0 = idx0; P.idx1 = idx1; P.idx2 = idx2;
    P.c0 = coords0; P.c1 = coords1; P.c2 = coords2; P.c3 = coords3; P.c4 = coords4;
    P.cnt = cnt; P.dslot = dslot; P.w3 = w3; P.z4 = z4; P.Wn = Wn;

    void* args[] = { &P };
    hipLaunchCooperativeKernel((const void*)weights_coop_kernel,
                               dim3(GRID_W), dim3(256), args, 0, stream);

    final_kernel<<<B * C, 256, 0, stream>>>(x, Wn, (float*)d_out, p);
}

// Round 12
// 48.887 us; speedup vs baseline: 3.7653x; 3.7653x over previous
//
#include <hip/hip_runtime.h>
#include <math.h>

// Problem constants (from reference setup_inputs)
constexpr int B  = 8;
constexpr int C  = 256;
constexpr int Q  = 85;              // C/D; channel->dim: d = min(c/Q, 2)
constexpr int NS0 = 16384, NS1 = 4096, NS2 = 1024, NS3 = 256;
constexpr int PAR = NS1 + NS2 + NS3;        // parents, levels 0-2
constexpr int SLT = NS0 + NS1 + NS2;        // slots (= children), levels 0-2

__device__ __forceinline__ int cdim(int c) {
    int d = c / Q;
    return d > 2 ? 2 : d;
}

// Sibling-group weight: given the 4 children of one parent (from dslot) and a
// target child node id, compute the target's per-dim weight and the per-dim
// sum over all 4 children.
__device__ __forceinline__ void sib_w(float4 c0, float4 c1, float4 c2, float4 c3,
                                      int target,
                                      float& wt0, float& wt1, float& wt2,
                                      float& zs0, float& zs1, float& zs2) {
    float mx0 = fmaxf(fmaxf(c0.x, c1.x), fmaxf(c2.x, c3.x));
    float mn0 = fminf(fminf(c0.x, c1.x), fminf(c2.x, c3.x));
    float mx1 = fmaxf(fmaxf(c0.y, c1.y), fmaxf(c2.y, c3.y));
    float mn1 = fminf(fminf(c0.y, c1.y), fminf(c2.y, c3.y));
    float mx2 = fmaxf(fmaxf(c0.z, c1.z), fmaxf(c2.z, c3.z));
    float mn2 = fminf(fminf(c0.z, c1.z), fminf(c2.z, c3.z));
    float pos0 = fmaxf(mx0, 0.f), neg0 = fminf(mn0, 0.f);
    float pos1 = fmaxf(mx1, 0.f), neg1 = fminf(mn1, 0.f);
    float pos2 = fmaxf(mx2, 0.f), neg2 = fminf(mn2, 0.f);

    zs0 = zs1 = zs2 = 0.f;
    wt0 = wt1 = wt2 = 0.f;
    float4 chs[4] = {c0, c1, c2, c3};
#pragma unroll
    for (int k = 0; k < 4; ++k) {
        float d0 = chs[k].x, d1 = chs[k].y, d2 = chs[k].z;
        int   n  = __float_as_int(chs[k].w);
        float wv0 = 1.f - fabsf(d0) / (fabsf(d0 >= 0.f ? pos0 : neg0) + 1e-6f);
        float wv1 = 1.f - fabsf(d1) / (fabsf(d1 >= 0.f ? pos1 : neg1) + 1e-6f);
        float wv2 = 1.f - fabsf(d2) / (fabsf(d2 >= 0.f ? pos2 : neg2) + 1e-6f);
        zs0 += wv0; zs1 += wv1; zs2 += wv2;
        if (n == target) { wt0 = wv0; wt1 = wv1; wt2 = wv2; }
    }
}

// ---------------------------------------------------------------------------
// Kernel 1: fused inversion (levels 0-2) + level-3 weights.
//  y<3 : per-child slot assignment + delta -> dslot.
//        slot = atomicAdd(cnt)&3 is correct from ANY counter start value
//        (4 consecutive returns are distinct mod 4) -> no init pass needed.
//  y==3: level-3 (single root) weights via deterministic LDS tree reduction.
// ---------------------------------------------------------------------------
__global__ void invert_fused_kernel(const int* __restrict__ idx0,
                                    const int* __restrict__ idx1,
                                    const int* __restrict__ idx2,
                                    const float* __restrict__ c0,
                                    const float* __restrict__ c1,
                                    const float* __restrict__ c2,
                                    const float* __restrict__ c3,
                                    const float* __restrict__ c4,
                                    unsigned* __restrict__ cnt,    // (B,PAR) no init needed
                                    float4*   __restrict__ dslot,  // (B,SLT)
                                    float*    __restrict__ w3,     // (B,256,3)
                                    float*    __restrict__ z4) {   // (B,3)
    __shared__ float sm[3][256];
    __shared__ float sn[3][256];

    if (blockIdx.y == 3) {
        // ---- level-3 weights (one block per batch, 8 blocks used) ----
        if (blockIdx.x >= 8) return;
        int b = blockIdx.x;
        int n = threadIdx.x;

        float pc0 = c4[b * 3 + 0], pc1 = c4[b * 3 + 1], pc2 = c4[b * 3 + 2];
        const float* cp = &c3[((size_t)(b * 256 + n)) * 3];
        float d0 = cp[0] - pc0, d1 = cp[1] - pc1, d2 = cp[2] - pc2;
        sm[0][n] = d0; sm[1][n] = d1; sm[2][n] = d2;
        sn[0][n] = d0; sn[1][n] = d1; sn[2][n] = d2;
        __syncthreads();
        for (int s = 128; s > 0; s >>= 1) {
            if (n < s) {
#pragma unroll
                for (int d = 0; d < 3; ++d) {
                    sm[d][n] = fmaxf(sm[d][n], sm[d][n + s]);
                    sn[d][n] = fminf(sn[d][n], sn[d][n + s]);
                }
            }
            __syncthreads();
        }
        float pos0 = fmaxf(sm[0][0], 0.f), pos1 = fmaxf(sm[1][0], 0.f), pos2 = fmaxf(sm[2][0], 0.f);
        float neg0 = fminf(sn[0][0], 0.f), neg1 = fminf(sn[1][0], 0.f), neg2 = fminf(sn[2][0], 0.f);
        __syncthreads();

        float w0 = 1.f - fabsf(d0) / (fabsf(d0 >= 0.f ? pos0 : neg0) + 1e-6f);
        float w1 = 1.f - fabsf(d1) / (fabsf(d1 >= 0.f ? pos1 : neg1) + 1e-6f);
        float w2 = 1.f - fabsf(d2) / (fabsf(d2 >= 0.f ? pos2 : neg2) + 1e-6f);
        float* wp = &w3[((size_t)(b * 256 + n)) * 3];
        wp[0] = w0; wp[1] = w1; wp[2] = w2;

        sm[0][n] = w0; sm[1][n] = w1; sm[2][n] = w2;
        __syncthreads();
        for (int s = 128; s > 0; s >>= 1) {
            if (n < s) {
#pragma unroll
                for (int d = 0; d < 3; ++d) sm[d][n] += sm[d][n + s];
            }
            __syncthreads();
        }
        if (n == 0) {
            z4[b * 3 + 0] = sm[0][0];
            z4[b * 3 + 1] = sm[1][0];
            z4[b * 3 + 2] = sm[2][0];
        }
        return;
    }

    // ---- levels 0-2 inversion ----
    int lvl = blockIdx.y;
    const int*   idx = (lvl == 0) ? idx0 : (lvl == 1 ? idx1 : idx2);
    const float* cc  = (lvl == 0) ? c0   : (lvl == 1 ? c1   : c2);
    const float* cn  = (lvl == 0) ? c1   : (lvl == 1 ? c2   : c3);
    int N  = (lvl == 0) ? NS0 : (lvl == 1 ? NS1 : NS2);
    int Nn = (lvl == 0) ? NS1 : (lvl == 1 ? NS2 : NS3);
    int cbase = (lvl == 0) ? 0 : (lvl == 1 ? NS1 : NS1 + NS2);
    int sbase = (lvl == 0) ? 0 : (lvl == 1 ? NS0 : NS0 + NS1);

    int t = blockIdx.x * blockDim.x + threadIdx.x;
    if (t >= B * N) return;
    int b = t / N;
    int n = t - b * N;
    int j = idx[t];
    int pj = b * Nn + j;

    unsigned o = atomicAdd(&cnt[(size_t)b * PAR + cbase + j], 1u);
    int slot = (int)(o & 3u);

    float4 dv;
    dv.x = cc[(size_t)t * 3 + 0] - cn[(size_t)pj * 3 + 0];
    dv.y = cc[(size_t)t * 3 + 1] - cn[(size_t)pj * 3 + 1];
    dv.z = cc[(size_t)t * 3 + 2] - cn[(size_t)pj * 3 + 2];
    dv.w = __int_as_float(n);
    dslot[((size_t)b * SLT + sbase + (size_t)j * 4) + slot] = dv;
}

// ---------------------------------------------------------------------------
// Kernel 2: self-contained leaf-weight chain, one thread per LEVEL-1 node.
// Reads its 4 leaves (64B), its parent's sibling group (64B) and its
// grandparent's sibling group (64B) straight from dslot (L2-shared), the
// root weights w3/z4, and writes the 4 leaves' effective Wn values.
// No intermediate w/z buffers at all. (Validated in R11 phase B: absmax 0.)
// ---------------------------------------------------------------------------
__global__ void leafwn_kernel(const float4* __restrict__ dslot, // (B,SLT)
                              const int*   __restrict__ idx1,   // (B,NS1)
                              const int*   __restrict__ idx2,   // (B,NS2)
                              const float* __restrict__ w3,     // (B,256,3)
                              const float* __restrict__ z4,     // (B,3)
                              float* __restrict__ Wn) {         // (B,3,NS0)
    int t = blockIdx.x * blockDim.x + threadIdx.x;
    if (t >= B * NS1) return;
    int b = t / NS1;
    int j = t - b * NS1;

    // Own 4 leaves.
    const float4* dp0 = &dslot[(size_t)b * SLT + (size_t)j * 4];
    float4 l0 = dp0[0], l1 = dp0[1], l2 = dp0[2], l3 = dp0[3];

    float mx0 = fmaxf(fmaxf(l0.x, l1.x), fmaxf(l2.x, l3.x));
    float mn0 = fminf(fminf(l0.x, l1.x), fminf(l2.x, l3.x));
    float mx1 = fmaxf(fmaxf(l0.y, l1.y), fmaxf(l2.y, l3.y));
    float mn1 = fminf(fminf(l0.y, l1.y), fminf(l2.y, l3.y));
    float mx2 = fmaxf(fmaxf(l0.z, l1.z), fmaxf(l2.z, l3.z));
    float mn2 = fminf(fminf(l0.z, l1.z), fminf(l2.z, l3.z));
    float pos0 = fmaxf(mx0, 0.f), neg0 = fminf(mn0, 0.f);
    float pos1 = fmaxf(mx1, 0.f), neg1 = fminf(mn1, 0.f);
    float pos2 = fmaxf(mx2, 0.f), neg2 = fminf(mn2, 0.f);

    float wv0[4], wv1[4], wv2[4];
    int   nid[4];
    float zz0 = 0.f, zz1 = 0.f, zz2 = 0.f;
    float4 chs[4] = {l0, l1, l2, l3};
#pragma unroll
    for (int k = 0; k < 4; ++k) {
        float d0 = chs[k].x, d1 = chs[k].y, d2 = chs[k].z;
        nid[k] = __float_as_int(chs[k].w);
        wv0[k] = 1.f - fabsf(d0) / (fabsf(d0 >= 0.f ? pos0 : neg0) + 1e-6f);
        wv1[k] = 1.f - fabsf(d1) / (fabsf(d1 >= 0.f ? pos1 : neg1) + 1e-6f);
        wv2[k] = 1.f - fabsf(d2) / (fabsf(d2 >= 0.f ? pos2 : neg2) + 1e-6f);
        zz0 += wv0[k]; zz1 += wv1[k]; zz2 += wv2[k];
    }

    // Parent (level-1 sibling group under L2 node a2).
    int a2 = idx1[t];
    const float4* dp1 = &dslot[(size_t)b * SLT + NS0 + (size_t)a2 * 4];
    float w1t0, w1t1, w1t2, z20, z21, z22;
    sib_w(dp1[0], dp1[1], dp1[2], dp1[3], j, w1t0, w1t1, w1t2, z20, z21, z22);

    // Grandparent (level-2 sibling group under L3 node a3).
    int a3 = idx2[(size_t)b * NS2 + a2];
    const float4* dp2 = &dslot[(size_t)b * SLT + NS0 + NS1 + (size_t)a3 * 4];
    float w2t0, w2t1, w2t2, z30, z31, z32;
    sib_w(dp2[0], dp2[1], dp2[2], dp2[3], a2, w2t0, w2t1, w2t2, z30, z31, z32);

    const float* w3p = &w3[((size_t)b * 256 + a3) * 3];
    float U0 = w1t0 / (z20 + 1e-6f) * w2t0 / (z30 + 1e-6f) * w3p[0] / (z4[b * 3 + 0] + 1e-6f);
    float U1 = w1t1 / (z21 + 1e-6f) * w2t1 / (z31 + 1e-6f) * w3p[1] / (z4[b * 3 + 1] + 1e-6f);
    float U2 = w1t2 / (z22 + 1e-6f) * w2t2 / (z32 + 1e-6f) * w3p[2] / (z4[b * 3 + 2] + 1e-6f);

    float r0 = U0 / (zz0 + 1e-6f);
    float r1 = U1 / (zz1 + 1e-6f);
    float r2 = U2 / (zz2 + 1e-6f);

    float* Wb0 = Wn + ((size_t)(b * 3 + 0)) * NS0;
    float* Wb1 = Wn + ((size_t)(b * 3 + 1)) * NS0;
    float* Wb2 = Wn + ((size_t)(b * 3 + 2)) * NS0;
#pragma unroll
    for (int k = 0; k < 4; ++k) {
        int n = nid[k];
        Wb0[n] = wv0[k] * r0;
        Wb1[n] = wv1[k] * r1;
        Wb2[n] = wv2[k] * r2;
    }
}

// ---------------------------------------------------------------------------
// Kernel 3: the whole hierarchy as one weighted reduction over leaves.
// out[b][c] = cbrt( sum_n max(x[b][c][n],eps)^3 * Wn[b][d(c)][n] )
// One block per (b,c); x read coalesced float4 exactly once.
// ---------------------------------------------------------------------------
__global__ void final_kernel(const float* __restrict__ x,   // (B,C,NS0)
                             const float* __restrict__ Wn,  // (B,3,NS0)
                             float* __restrict__ out,       // (B,C)
                             const float* __restrict__ p_arr) {
    __shared__ float sred[256];
    int bc = blockIdx.x;
    int b = bc / C;
    int c = bc - b * C;
    int d = cdim(c);
    float p = p_arr[0];
    bool p3 = (p == 3.0f);

    const float4* xr = (const float4*)(x + (size_t)bc * NS0);
    const float4* wr = (const float4*)(Wn + ((size_t)(b * 3 + d)) * NS0);

    float acc = 0.f;
#pragma unroll 8
    for (int i = threadIdx.x; i < NS0 / 4; i += 256) {
        float4 xv = xr[i];
        float4 wv = wr[i];
        float v0 = fmaxf(xv.x, 1e-6f);
        float v1 = fmaxf(xv.y, 1e-6f);
        float v2 = fmaxf(xv.z, 1e-6f);
        float v3 = fmaxf(xv.w, 1e-6f);
        float s0 = p3 ? v0 * v0 * v0 : powf(v0, p);
        float s1 = p3 ? v1 * v1 * v1 : powf(v1, p);
        float s2 = p3 ? v2 * v2 * v2 : powf(v2, p);
        float s3 = p3 ? v3 * v3 * v3 : powf(v3, p);
        acc = fmaf(s0, wv.x, acc);
        acc = fmaf(s1, wv.y, acc);
        acc = fmaf(s2, wv.z, acc);
        acc = fmaf(s3, wv.w, acc);
    }
    sred[threadIdx.x] = acc;
    __syncthreads();
    for (int s = 128; s > 0; s >>= 1) {
        if (threadIdx.x < s) sred[threadIdx.x] += sred[threadIdx.x + s];
        __syncthreads();
    }
    if (threadIdx.x == 0) {
        float t = sred[0];
        out[bc] = p3 ? cbrtf(t) : powf(t, 1.0f / p);
    }
}

// ---------------------------------------------------------------------------
extern "C" void kernel_launch(void* const* d_in, const int* in_sizes, int n_in,
                              void* d_out, int out_size, void* d_ws, size_t ws_size,
                              hipStream_t stream) {
    const float* x      = (const float*)d_in[0];
    const int*   idx0   = (const int*)d_in[1];
    const int*   idx1   = (const int*)d_in[2];
    const int*   idx2   = (const int*)d_in[3];
    // d_in[4] (idx3) unused: level-3 parent is the single root node.
    const float* coords0 = (const float*)d_in[5];
    const float* coords1 = (const float*)d_in[6];
    const float* coords2 = (const float*)d_in[7];
    const float* coords3 = (const float*)d_in[8];
    const float* coords4 = (const float*)d_in[9];
    const float* p = (const float*)d_in[10];

    // Workspace carve-up (256B aligned)
    char* ws = (char*)d_ws;
    size_t off = 0;
    auto alloc = [&](size_t bytes) -> void* {
        off = (off + 255) & ~(size_t)255;
        void* r = ws + off;
        off += bytes;
        return r;
    };

    unsigned* cnt  = (unsigned*)alloc((size_t)B * PAR * sizeof(unsigned)); // never initialized (mod-4 trick)
    float4*  dslot = (float4*)alloc((size_t)B * SLT * sizeof(float4));
    float* w3 = (float*)alloc((size_t)B * NS3 * 3 * sizeof(float));
    float* z4 = (float*)alloc((size_t)B * 1   * 3 * sizeof(float));
    float* Wn = (float*)alloc((size_t)B * 3 * NS0 * sizeof(float));

    dim3 ig((B * NS0 + 255) / 256, 4);     // y=0..2: invert levels; y=3: level-3 weights
    invert_fused_kernel<<<ig, 256, 0, stream>>>(
        idx0, idx1, idx2, coords0, coords1, coords2, coords3, coords4,
        cnt, dslot, w3, z4);

    leafwn_kernel<<<(B * NS1 + 255) / 256, 256, 0, stream>>>(
        dslot, idx1, idx2, w3, z4, Wn);

    final_kernel<<<B * C, 256, 0, stream>>>(x, Wn, (float*)d_out, p);
}